// Round 4
// baseline (141.574 us; speedup 1.0000x reference)
//
#include <hip/hip_runtime.h>

#define NQ 22
#define DIM (1 << NQ)
#define TILE 4096
#define LOG_TILE 12
#define NBLK (DIM / TILE)   // 1024 blocks, h = 10 bits (global bits 12..21)
#define NTHR 512            // 8 waves/block, 8 elements/thread

typedef float f32x4_t __attribute__((ext_vector_type(4)));

// Precompute B[l] = sum over pairs p>q (LSB positions 0..11) both set in l of
// U[(21-p)*22 + (21-q)].  4096 entries, written to workspace (16 KB).
__global__ __launch_bounds__(256) void ryd_precompute_B(const float* __restrict__ U,
                                                        float* __restrict__ Btab) {
    int t = blockIdx.x * blockDim.x + threadIdx.x;  // 0..4095
    __shared__ float Us[NQ * NQ];
    for (int i = threadIdx.x; i < NQ * NQ; i += blockDim.x) Us[i] = U[i];
    __syncthreads();
    float b = 0.f;
    #pragma unroll
    for (int p = 1; p <= 11; ++p) {
        if ((t >> p) & 1) {
            #pragma unroll
            for (int q = 0; q < p; ++q) {
                if ((t >> q) & 1) b += Us[(21 - p) * NQ + (21 - q)];
            }
        }
    }
    Btab[t] = b;
}

#define ACC8(a0, a1, b0, b1)                                              \
    do {                                                                  \
        ar[0] += (a0).x; ar[1] += (a0).y; ar[2] += (a0).z; ar[3] += (a0).w; \
        ar[4] += (a1).x; ar[5] += (a1).y; ar[6] += (a1).z; ar[7] += (a1).w; \
        ai[0] += (b0).x; ai[1] += (b0).y; ai[2] += (b0).z; ai[3] += (b0).w; \
        ai[4] += (b1).x; ai[5] += (b1).y; ai[6] += (b1).z; ai[7] += (b1).w; \
    } while (0)

// Accumulate from ext-vector f32x4_t quads (NT-loaded flips).
#define ACC8V(a0, a1, b0, b1)                                                   \
    do {                                                                        \
        ar[0] += (a0)[0]; ar[1] += (a0)[1]; ar[2] += (a0)[2]; ar[3] += (a0)[3]; \
        ar[4] += (a1)[0]; ar[5] += (a1)[1]; ar[6] += (a1)[2]; ar[7] += (a1)[3]; \
        ai[0] += (b0)[0]; ai[1] += (b0)[1]; ai[2] += (b0)[2]; ai[3] += (b0)[3]; \
        ai[4] += (b1)[0]; ai[5] += (b1)[1]; ai[6] += (b1)[2]; ai[7] += (b1)[3]; \
    } while (0)

// Issue the 4 float4 loads of one partner tile into NAMED registers.
#define LOAD_FLIP(v, bit)                                                 \
    float4 v##r0, v##r1, v##i0, v##i1;                                    \
    {                                                                     \
        const int pb_ = ((h ^ (bit)) << LOG_TILE) + m0;                   \
        v##r0 = *(const float4*)(sr_g + pb_);                             \
        v##r1 = *(const float4*)(sr_g + pb_ + 4);                         \
        v##i0 = *(const float4*)(si_g + pb_);                             \
        v##i1 = *(const float4*)(si_g + pb_ + 4);                         \
    }

// Non-temporal variant for the 3 cross-XCD flips: those lines are touched
// exactly once per XCD (h^1,h^2,h^4 with h%8 fixed) — evict-first so they
// don't thrash the 4 MB same-XCD working set out of L2.  NT builtin needs
// ext-vector pointee, not HIP_vector_type.
#define LOAD_FLIP_NT(v, bit)                                                      \
    f32x4_t v##r0, v##r1, v##i0, v##i1;                                           \
    {                                                                             \
        const int pb_ = ((h ^ (bit)) << LOG_TILE) + m0;                           \
        v##r0 = __builtin_nontemporal_load((const f32x4_t*)(sr_g + pb_));         \
        v##r1 = __builtin_nontemporal_load((const f32x4_t*)(sr_g + pb_ + 4));     \
        v##i0 = __builtin_nontemporal_load((const f32x4_t*)(si_g + pb_));         \
        v##i1 = __builtin_nontemporal_load((const f32x4_t*)(si_g + pb_ + 4));     \
    }

#define CONSUME(v)    ACC8(v##r0, v##r1, v##i0, v##i1)
#define CONSUME_NT(v) ACC8V(v##r0, v##r1, v##i0, v##i1)

// LDS chunk swizzle (16B granularity): spreads one wave's ds_read_b128 lanes
// across all 8 bank groups.
__device__ __forceinline__ int swz(int c) { return c ^ ((c >> 3) & 1); }

// 4 waves/EU min -> VGPR cap 128, target 2 blocks (16 waves)/CU resident.
__global__ __launch_bounds__(NTHR, 4) void ryd_main(
    const float* __restrict__ sr_g, const float* __restrict__ si_g,
    const float* __restrict__ rabi, const float* __restrict__ detune,
    const float* __restrict__ U, const float* __restrict__ Btab,
    float* __restrict__ out) {
    __shared__ float4 srv[TILE / 4];   // swizzled 16B chunks, 16 KB
    __shared__ float4 siv[TILE / 4];   // 16 KB
    __shared__ float AD[13];  // AD[0..11] = Dq[q] (cross sums), AD[12] = A(h)

    const int h = blockIdx.x;        // high 10 bits of the basis index
    const int tid = threadIdx.x;     // 0..511
    const int m0 = tid << 3;         // local element base (this thread owns 8)
    const int base = h << LOG_TILE;  // global tile base

    // ---- (1) Own tile: first in the vm FIFO, so LDS staging waits only on these.
    float4 r0 = *(const float4*)(sr_g + base + m0);
    float4 r1 = *(const float4*)(sr_g + base + m0 + 4);
    float4 i0 = *(const float4*)(si_g + base + m0);
    float4 i1 = *(const float4*)(si_g + base + m0 + 4);

    // ---- (2) Cross-XCD partner tiles (h-bits 0..2, global bits 12..14).
    // Longest latency path: in flight across the whole LDS phase. NT: single-use.
    LOAD_FLIP_NT(f0, 1)
    LOAD_FLIP_NT(f1, 2)
    LOAD_FLIP_NT(f2, 4)

    // ---- (3) Batch A of same-XCD flips: also in flight across the LDS phase.
    LOAD_FLIP(g3, 8)
    LOAD_FLIP(g4, 16)
    LOAD_FLIP(g5, 32)

    // ---- Stage own tile to LDS (swizzled chunks); waits only on the 4 own loads.
    srv[swz(2 * tid)]     = r0;
    srv[swz(2 * tid + 1)] = r1;
    siv[swz(2 * tid)]     = i0;
    siv[swz(2 * tid + 1)] = i1;

    // Threads 0..11: Dq[q] = sum_{hp set in h, hp in 0..9} U[(9-hp)*22 + (21-q)]
    // Thread 12:     A(h)  = sum over pairs hp>hq set in h of U[(9-hp)*22 + (9-hq)]
    if (tid < 12) {
        int q = tid;
        float d = 0.f;
        #pragma unroll
        for (int hp = 0; hp <= 9; ++hp)
            if ((h >> hp) & 1) d += U[(9 - hp) * NQ + (21 - q)];
        AD[q] = d;
    } else if (tid == 12) {
        float a = 0.f;
        #pragma unroll
        for (int hp = 1; hp <= 9; ++hp) {
            if ((h >> hp) & 1) {
                #pragma unroll
                for (int hq = 0; hq < hp; ++hq)
                    if ((h >> hq) & 1) a += U[(9 - hp) * NQ + (9 - hq)];
            }
        }
        AD[12] = a;
    }

    float pr[8]  = {r0.x, r0.y, r0.z, r0.w, r1.x, r1.y, r1.z, r1.w};
    float pi_[8] = {i0.x, i0.y, i0.z, i0.w, i1.x, i1.y, i1.z, i1.w};

    __syncthreads();

    // ---- Flip bits 0..2: partners live in this thread's own registers.
    float ar[8], ai[8];
    #pragma unroll
    for (int e = 0; e < 8; ++e) {
        ar[e] = pr[e ^ 1] + pr[e ^ 2] + pr[e ^ 4];
        ai[e] = pi_[e ^ 1] + pi_[e ^ 2] + pi_[e ^ 4];
    }

    // ---- Flip bits 3..11: partner 8-blocks inside the LDS tile (swizzled b128).
    #pragma unroll
    for (int jj = 0; jj < 9; ++jj) {
        int p = tid ^ (1 << jj);
        float4 a0 = srv[swz(2 * p)];
        float4 a1 = srv[swz(2 * p + 1)];
        float4 b0 = siv[swz(2 * p)];
        float4 b1 = siv[swz(2 * p + 1)];
        ACC8(a0, a1, b0, b1);
    }

    // ---- Batch B issued before any global consumption: FIFO stays deep.
    LOAD_FLIP(g6, 64)
    LOAD_FLIP(g7, 128)

    // ---- Consume cross-XCD prefetch (latency hidden by the LDS phase).
    CONSUME_NT(f0);
    CONSUME_NT(f1);
    CONSUME_NT(f2);

    // ---- Batch C + Btab issued before consuming batch A.
    LOAD_FLIP(g8, 256)
    LOAD_FLIP(g9, 512)
    float4 B0 = *(const float4*)(Btab + m0);
    float4 B1 = *(const float4*)(Btab + m0 + 4);

    // ---- Consume A, then B, then C (FIFO order, waits always counted-deep).
    CONSUME(g3);
    CONSUME(g4);
    CONSUME(g5);
    CONSUME(g6);
    CONSUME(g7);
    CONSUME(g8);
    CONSUME(g9);

    // ---- Diagonal: diag(b) = A + B[l] + sum_{q set in l} Dq[q] - det*popc(b)
    const float det = detune[0];
    const float hrabi = 0.5f * rabi[0];
    float Dq0 = AD[0] - det;
    float Dq1 = AD[1] - det;
    float Dq2 = AD[2] - det;
    float diagBase = AD[12] - det * (float)__popc((unsigned)h);
    #pragma unroll
    for (int j = 0; j < 9; ++j)
        if ((tid >> j) & 1) diagBase += AD[j + 3] - det;

    float Bv[8] = {B0.x, B0.y, B0.z, B0.w, B1.x, B1.y, B1.z, B1.w};

    float orv[8], oiv[8];
    #pragma unroll
    for (int e = 0; e < 8; ++e) {
        float d = diagBase + Bv[e];
        if (e & 1) d += Dq0;
        if (e & 2) d += Dq1;
        if (e & 4) d += Dq2;
        orv[e] = hrabi * ar[e] + d * pr[e];
        oiv[e] = hrabi * ai[e] + d * pi_[e];
    }

    // ---- Non-temporal stores: keep the write stream from evicting the
    // partner-read working set out of L2.
    f32x4_t o0 = {orv[0], orv[1], orv[2], orv[3]};
    f32x4_t o1 = {orv[4], orv[5], orv[6], orv[7]};
    f32x4_t o2 = {oiv[0], oiv[1], oiv[2], oiv[3]};
    f32x4_t o3 = {oiv[4], oiv[5], oiv[6], oiv[7]};
    __builtin_nontemporal_store(o0, (f32x4_t*)(out + base + m0));
    __builtin_nontemporal_store(o1, (f32x4_t*)(out + base + m0 + 4));
    __builtin_nontemporal_store(o2, (f32x4_t*)(out + DIM + base + m0));
    __builtin_nontemporal_store(o3, (f32x4_t*)(out + DIM + base + m0 + 4));
}

extern "C" void kernel_launch(void* const* d_in, const int* in_sizes, int n_in,
                              void* d_out, int out_size, void* d_ws, size_t ws_size,
                              hipStream_t stream) {
    const float* state_real = (const float*)d_in[0];
    const float* state_imag = (const float*)d_in[1];
    const float* rabi       = (const float*)d_in[2];
    const float* detune     = (const float*)d_in[3];
    const float* U          = (const float*)d_in[4];
    float* Btab = (float*)d_ws;  // 4096 floats = 16 KB
    float* out  = (float*)d_out;

    ryd_precompute_B<<<TILE / 256, 256, 0, stream>>>(U, Btab);
    ryd_main<<<NBLK, NTHR, 0, stream>>>(state_real, state_imag, rabi, detune,
                                        U, Btab, out);
}

// Round 5
// 132.445 us; speedup vs baseline: 1.0689x; 1.0689x over previous
//
#include <hip/hip_runtime.h>

#define NQ 22
#define DIM (1 << NQ)
#define TILE 2048
#define LOG_TILE 11

typedef float f32x4_t __attribute__((ext_vector_type(4)));

// Precompute B[l] = sum over pairs p>q (LSB positions 0..10) both set in l of
// U[(21-p)*22 + (21-q)].  2048 entries, written to workspace (8 KB).
__global__ __launch_bounds__(256) void ryd_precompute_B(const float* __restrict__ U,
                                                        float* __restrict__ Btab) {
    int t = blockIdx.x * blockDim.x + threadIdx.x;  // 0..2047
    __shared__ float Us[NQ * NQ];
    for (int i = threadIdx.x; i < NQ * NQ; i += blockDim.x) Us[i] = U[i];
    __syncthreads();
    float b = 0.f;
    #pragma unroll
    for (int p = 1; p <= 10; ++p) {
        if ((t >> p) & 1) {
            #pragma unroll
            for (int q = 0; q < p; ++q) {
                if ((t >> q) & 1) b += Us[(21 - p) * NQ + (21 - q)];
            }
        }
    }
    Btab[t] = b;
}

#define ACC8(a0, a1, b0, b1)                                              \
    do {                                                                  \
        ar[0] += (a0).x; ar[1] += (a0).y; ar[2] += (a0).z; ar[3] += (a0).w; \
        ar[4] += (a1).x; ar[5] += (a1).y; ar[6] += (a1).z; ar[7] += (a1).w; \
        ai[0] += (b0).x; ai[1] += (b0).y; ai[2] += (b0).z; ai[3] += (b0).w; \
        ai[4] += (b1).x; ai[5] += (b1).y; ai[6] += (b1).z; ai[7] += (b1).w; \
    } while (0)

// LDS chunk swizzle (16B granularity): spreads one wave's ds_read_b128 lanes
// across all 8 bank groups.
__device__ __forceinline__ int swz(int c) { return c ^ ((c >> 3) & 1); }

// ---------------------------------------------------------------------------
// Pass A: per 2048-tile — register flips (bits 0..2), LDS flips (bits 3..10),
// full diagonal.  Pure streaming: ONE global load-wait point per block.
// Plain stores: out is re-read by pass B, keep it cached.
// ---------------------------------------------------------------------------
__global__ __launch_bounds__(256) void ryd_rows(
    const float* __restrict__ sr_g, const float* __restrict__ si_g,
    const float* __restrict__ rabi, const float* __restrict__ detune,
    const float* __restrict__ U, const float* __restrict__ Btab,
    float* __restrict__ out) {
    __shared__ float4 srv[TILE / 4];   // swizzled 16B chunks, 8 KB
    __shared__ float4 siv[TILE / 4];   // 8 KB
    __shared__ float AD[12];  // AD[0..10] = Dq[q] (cross sums), AD[11] = A(h)

    const int h = blockIdx.x;        // high 11 bits of the basis index
    const int tid = threadIdx.x;     // 0..255
    const int m0 = tid << 3;         // local element base (this thread owns 8)
    const int base = h << LOG_TILE;  // global tile base

    float4 r0 = *(const float4*)(sr_g + base + m0);
    float4 r1 = *(const float4*)(sr_g + base + m0 + 4);
    float4 i0 = *(const float4*)(si_g + base + m0);
    float4 i1 = *(const float4*)(si_g + base + m0 + 4);

    float4 B0 = *(const float4*)(Btab + m0);
    float4 B1 = *(const float4*)(Btab + m0 + 4);

    srv[swz(2 * tid)]     = r0;
    srv[swz(2 * tid + 1)] = r1;
    siv[swz(2 * tid)]     = i0;
    siv[swz(2 * tid + 1)] = i1;

    // Threads 0..10: Dq[q] = sum_{hp set in h} U[(10-hp)*22 + (21-q)]
    // Thread 11:     A(h)  = sum over pairs hp>hq set in h of U[(10-hp)*22+(10-hq)]
    if (tid < 11) {
        int q = tid;
        float d = 0.f;
        #pragma unroll
        for (int hp = 0; hp <= 10; ++hp)
            if ((h >> hp) & 1) d += U[(10 - hp) * NQ + (21 - q)];
        AD[q] = d;
    } else if (tid == 11) {
        float a = 0.f;
        #pragma unroll
        for (int hp = 1; hp <= 10; ++hp) {
            if ((h >> hp) & 1) {
                #pragma unroll
                for (int hq = 0; hq < hp; ++hq)
                    if ((h >> hq) & 1) a += U[(10 - hp) * NQ + (10 - hq)];
            }
        }
        AD[11] = a;
    }

    float pr[8]  = {r0.x, r0.y, r0.z, r0.w, r1.x, r1.y, r1.z, r1.w};
    float pi_[8] = {i0.x, i0.y, i0.z, i0.w, i1.x, i1.y, i1.z, i1.w};

    __syncthreads();

    // Flip bits 0..2: partners in this thread's own registers.
    float ar[8], ai[8];
    #pragma unroll
    for (int e = 0; e < 8; ++e) {
        ar[e] = pr[e ^ 1] + pr[e ^ 2] + pr[e ^ 4];
        ai[e] = pi_[e ^ 1] + pi_[e ^ 2] + pi_[e ^ 4];
    }

    // Flip bits 3..10: partner 8-blocks inside the LDS tile (swizzled b128).
    #pragma unroll
    for (int jj = 0; jj < 8; ++jj) {
        int p = tid ^ (1 << jj);
        float4 a0 = srv[swz(2 * p)];
        float4 a1 = srv[swz(2 * p + 1)];
        float4 b0 = siv[swz(2 * p)];
        float4 b1 = siv[swz(2 * p + 1)];
        ACC8(a0, a1, b0, b1);
    }

    // Diagonal: diag(b) = A + B[l] + sum_{q set in l} Dq[q] - det*popc(b)
    const float det = detune[0];
    const float hrabi = 0.5f * rabi[0];
    float Dq0 = AD[0] - det;
    float Dq1 = AD[1] - det;
    float Dq2 = AD[2] - det;
    float diagBase = AD[11] - det * (float)__popc((unsigned)h);
    #pragma unroll
    for (int j = 0; j < 8; ++j)
        if ((tid >> j) & 1) diagBase += AD[j + 3] - det;

    float Bv[8] = {B0.x, B0.y, B0.z, B0.w, B1.x, B1.y, B1.z, B1.w};

    float orv[8], oiv[8];
    #pragma unroll
    for (int e = 0; e < 8; ++e) {
        float d = diagBase + Bv[e];
        if (e & 1) d += Dq0;
        if (e & 2) d += Dq1;
        if (e & 4) d += Dq2;
        orv[e] = hrabi * ar[e] + d * pr[e];
        oiv[e] = hrabi * ai[e] + d * pi_[e];
    }

    *(float4*)(out + base + m0)           = make_float4(orv[0], orv[1], orv[2], orv[3]);
    *(float4*)(out + base + m0 + 4)       = make_float4(orv[4], orv[5], orv[6], orv[7]);
    *(float4*)(out + DIM + base + m0)     = make_float4(oiv[0], oiv[1], oiv[2], oiv[3]);
    *(float4*)(out + DIM + base + m0 + 4) = make_float4(oiv[4], oiv[5], oiv[6], oiv[7]);
}

// ---------------------------------------------------------------------------
// Pass B: flips of the high 11 bits.  psi viewed as [hi=2048][lo=2048]; each
// block owns a 2048-row x 16-col slice of ONE array (re or im): load it into
// LDS (full 64B lines, coalesced), do all 11 hi-bit flips as LDS b128 reads,
// RMW-add hrabi*S2 into out (NT: single-use lines).
// ---------------------------------------------------------------------------
__global__ __launch_bounds__(1024, 4) void ryd_cols(
    const float* __restrict__ sr_g, const float* __restrict__ si_g,
    const float* __restrict__ rabi, float* __restrict__ out) {
    __shared__ f32x4_t L[TILE * 4];  // [row 0..2047][cv 0..3], 128 KB

    const int b = blockIdx.x;        // 0..255
    const int A = b & 1;             // 0 = real, 1 = imag
    const int C0 = (b >> 1) << 4;    // column base (multiple of 16 -> 64B lines)
    const float* __restrict__ src = A ? si_g : sr_g;
    float* __restrict__ dst = out + (A ? DIM : 0);
    const int t = threadIdx.x;       // 0..1023
    const float hrabi = 0.5f * rabi[0];

    // Load: cell n = (row r, colvec cv).  Lanes 0..3 cover one full 64B line.
    #pragma unroll
    for (int k = 0; k < 8; ++k) {
        int n = t + (k << 10);
        int r = n >> 2, cv = n & 3;
        L[(r << 2) + cv] = *(const f32x4_t*)(src + (r << 11) + C0 + (cv << 2));
    }
    __syncthreads();

    // Flip-sum over hi bits 0..10 (global bits 11..21), then RMW into out.
    #pragma unroll
    for (int k = 0; k < 8; ++k) {
        int n = t + (k << 10);
        int r = n >> 2, cv = n & 3;
        f32x4_t acc = L[((r ^ 1) << 2) + cv];
        #pragma unroll
        for (int j = 1; j < 11; ++j)
            acc += L[(((r ^ (1 << j)) << 2)) + cv];
        float* o = dst + (r << 11) + C0 + (cv << 2);
        f32x4_t cur = __builtin_nontemporal_load((const f32x4_t*)o);
        f32x4_t res = cur + acc * hrabi;
        __builtin_nontemporal_store(res, (f32x4_t*)o);
    }
}

extern "C" void kernel_launch(void* const* d_in, const int* in_sizes, int n_in,
                              void* d_out, int out_size, void* d_ws, size_t ws_size,
                              hipStream_t stream) {
    const float* state_real = (const float*)d_in[0];
    const float* state_imag = (const float*)d_in[1];
    const float* rabi       = (const float*)d_in[2];
    const float* detune     = (const float*)d_in[3];
    const float* U          = (const float*)d_in[4];
    float* Btab = (float*)d_ws;  // 2048 floats = 8 KB
    float* out  = (float*)d_out;

    ryd_precompute_B<<<TILE / 256, 256, 0, stream>>>(U, Btab);
    ryd_rows<<<DIM / TILE, 256, 0, stream>>>(state_real, state_imag, rabi, detune,
                                             U, Btab, out);
    ryd_cols<<<256, 1024, 0, stream>>>(state_real, state_imag, rabi, out);
}